// Round 6
// baseline (1342.801 us; speedup 1.0000x reference)
//
#include <hip/hip_runtime.h>
#include <hip/hip_cooperative_groups.h>

namespace cg = cooperative_groups;

#define N_NODES 50000
#define N_EDGES 800000
#define NTILES  (N_EDGES / 16)
// IN_F = 64, OUT_F = 64, EDGE_F = 16. edge_index int32[2*E]: src=ei[e], dst=ei[E+e].
//
// One cooperative kernel, phases separated by grid.sync():
//   P0: zero out+cnt, xa=x@W1[0:64], xb=x@W1[64:128]
//   P1: hist(dst) -> cnt
//   P2: grid-wide exclusive scan of cnt (block scan + block0 scan of partials)
//   P3: scatter: perm/ssrc/sdst sorted by dst (cursor = atomic on cnt)
//   P4: 16-edge MFMA tiles + run-merge epilogue (~6M atomics, wall ~274 G/s is fine)
// Cross-XCD: __threadfence() (agent wbL2/inv) brackets every grid.sync();
// cursor handoff is atomic-RMW end-to-end.
// RULE: __shfl only in wave-uniform control flow (round-4 lesson).

typedef __attribute__((ext_vector_type(8))) short bf16x8;  // 8 bf16 = 4 VGPRs
typedef __attribute__((ext_vector_type(4))) float f32x4;

__device__ inline short f2bf(float f) {       // fp32 -> bf16 bits, RNE
    union { float f; unsigned u; } v; v.f = f;
    unsigned r = v.u + 0x7FFFu + ((v.u >> 16) & 1u);
    return (short)(r >> 16);
}

// ---------------------------------------------------------------------------
// pre phase: xa = x @ W1[0:64,:], xb = x @ W1[64:128,:]  (per-wave, any #waves)
// ---------------------------------------------------------------------------
__device__ __forceinline__ void pre_phase(
    int gw, int nwaves, int j,
    const float* __restrict__ x, const float* __restrict__ W1,
    float* __restrict__ xa, float* __restrict__ xb)
{
    const int p = gw & 1;
    const int pair = gw >> 1;
    const int npair = nwaves >> 1;

    float wc[64];
#pragma unroll
    for (int k = 0; k < 64; ++k) wc[k] = W1[(p * 64 + k) * 64 + j];

    float* __restrict__ outp = p ? xb : xa;

    for (int i = pair; i < N_NODES; i += npair) {
        const float4* xr = (const float4*)&x[(long)i * 64];
        float a0 = 0.f, a1 = 0.f, a2 = 0.f, a3 = 0.f;
#pragma unroll
        for (int k4 = 0; k4 < 16; ++k4) {
            float4 xv = xr[k4];
            a0 += xv.x * wc[k4 * 4 + 0];
            a1 += xv.y * wc[k4 * 4 + 1];
            a2 += xv.z * wc[k4 * 4 + 2];
            a3 += xv.w * wc[k4 * 4 + 3];
        }
        outp[(long)i * 64 + j] = (a0 + a1) + (a2 + a3);
    }
}

// ---------------------------------------------------------------------------
// edge phase: tiles of 16 dst-sorted edges (shared by fused + fallback)
//   C1(16x64) = EA(16x16 pad32) @ W1c ; h = relu(C1 + xa[src]+xb[dst]+b1)
//   C2(16x64) = h @ W2 ; run-merge equal-dst rows -> one atomic per run
// MFMA 16x16x32: A: m=lane&15,k=(lane>>4)*8+i ; B: n=lane&15 same k
//                C: n=lane&15, m=(lane>>4)*4+r
// ---------------------------------------------------------------------------
union __align__(16) TileMem {
    unsigned short h[16][72];   // bf16 hidden (used first)
    float          m[16][68];   // fp32 msg (used after h is consumed)
};

__device__ __forceinline__ void edge_phase(
    int gw, int nwaves, int w, int l,
    const float* __restrict__ xa, const float* __restrict__ xb,
    const int* __restrict__ perm, const int* __restrict__ ssrc,
    const int* __restrict__ sdst,
    const float* __restrict__ edge_attr,
    const float* __restrict__ W1, const float* __restrict__ b1,
    const float* __restrict__ W2, const float* __restrict__ b2,
    float* __restrict__ out)
{
    __shared__ TileMem tls[4];
    __shared__ int dstbuf[4][16];

    const int n = l & 15;          // C col / A row / B col
    const int q = l >> 4;          // quad

    bf16x8 w1f[4];                 // W1 rows 128..143 (K-padded)
    bf16x8 w2f[4][2];
    float b1v[4], b2v[4];
#pragma unroll
    for (int t = 0; t < 4; ++t) {
        const int col = t * 16 + n;
#pragma unroll
        for (int i = 0; i < 8; ++i) {
            const int k = q * 8 + i;
            w1f[t][i] = (q < 2) ? f2bf(W1[(128 + k) * 64 + col]) : (short)0;
            w2f[t][0][i] = f2bf(W2[k * 64 + col]);
            w2f[t][1][i] = f2bf(W2[(32 + k) * 64 + col]);
        }
        b1v[t] = b1[col];
        b2v[t] = b2[col];
    }

    for (int tile = gw; tile < NTILES; tile += nwaves) {
        const long eb = (long)tile * 16;

        // direct loads (all lanes, row = l&15): one 64B segment each
        const int pev = perm[eb + n];
        const int sv  = ssrc[eb + n];
        const int dv  = sdst[eb + n];
        if (l < 16) dstbuf[w][n] = dv;

        // uniform-exec shfls
        int srcr[4], dstr[4];
#pragma unroll
        for (int r = 0; r < 4; ++r) {
            srcr[r] = __shfl(sv, q * 4 + r);
            dstr[r] = __shfl(dv, q * 4 + r);
        }

        // edge_attr A-fragment (K pad: quads 2,3 zero)
        bf16x8 eaf;
        if (q < 2) {
            const float* ep = &edge_attr[(long)pev * 16 + q * 8];
            float4 e0 = *(const float4*)ep;
            float4 e1 = *(const float4*)(ep + 4);
            eaf[0] = f2bf(e0.x); eaf[1] = f2bf(e0.y);
            eaf[2] = f2bf(e0.z); eaf[3] = f2bf(e0.w);
            eaf[4] = f2bf(e1.x); eaf[5] = f2bf(e1.y);
            eaf[6] = f2bf(e1.z); eaf[7] = f2bf(e1.w);
        } else {
#pragma unroll
            for (int i = 0; i < 8; ++i) eaf[i] = (short)0;
        }

        // GEMM1c
        f32x4 c1[4];
#pragma unroll
        for (int t = 0; t < 4; ++t) {
            f32x4 z = {0.f, 0.f, 0.f, 0.f};
            c1[t] = __builtin_amdgcn_mfma_f32_16x16x32_bf16(eaf, w1f[t], z, 0, 0, 0);
        }

        // gather xa[src]+xb[dst] in C layout (xb near-uniform after sort)
        float g[4][4];
#pragma unroll
        for (int t = 0; t < 4; ++t)
#pragma unroll
            for (int r = 0; r < 4; ++r)
                g[t][r] = xa[(long)srcr[r] * 64 + t * 16 + n]
                        + xb[(long)dstr[r] * 64 + t * 16 + n];

        // h = relu(c1+g+b1) -> bf16 -> LDS (C layout)
#pragma unroll
        for (int t = 0; t < 4; ++t)
#pragma unroll
            for (int r = 0; r < 4; ++r) {
                const float h = fmaxf(c1[t][r] + g[t][r] + b1v[t], 0.f);
                tls[w].h[q * 4 + r][t * 16 + n] = (unsigned short)f2bf(h);
            }

        // h as A-fragments (wave-internal, DS in-order)
        bf16x8 hf0 = *(const bf16x8*)&tls[w].h[n][q * 8];
        bf16x8 hf1 = *(const bf16x8*)&tls[w].h[n][32 + q * 8];

        // GEMM2
        f32x4 c2[4];
#pragma unroll
        for (int t = 0; t < 4; ++t) {
            f32x4 z = {0.f, 0.f, 0.f, 0.f};
            c2[t] = __builtin_amdgcn_mfma_f32_16x16x32_bf16(hf0, w2f[t][0], z, 0, 0, 0);
            c2[t] = __builtin_amdgcn_mfma_f32_16x16x32_bf16(hf1, w2f[t][1], c2[t], 0, 0, 0);
        }

        // msg -> LDS row-major (overlays h: h fully consumed above)
#pragma unroll
        for (int t = 0; t < 4; ++t)
#pragma unroll
            for (int r = 0; r < 4; ++r)
                tls[w].m[q * 4 + r][t * 16 + n] = c2[t][r] + b2v[t];

        // run-merge: lane l owns column l; rows sorted by dst (uniform branches)
        {
            int cur = dstbuf[w][0];
            float acc = tls[w].m[0][l];
#pragma unroll
            for (int r16 = 1; r16 < 16; ++r16) {
                const int d2 = dstbuf[w][r16];
                const float v = tls[w].m[r16][l];
                if (d2 != cur) {
                    unsafeAtomicAdd(&out[(long)cur * 64 + l], acc);
                    cur = d2; acc = v;
                } else {
                    acc += v;
                }
            }
            unsafeAtomicAdd(&out[(long)cur * 64 + l], acc);
        }
    }
}

// ---------------------------------------------------------------------------
// THE fused cooperative kernel
// ---------------------------------------------------------------------------
__global__ __launch_bounds__(256, 4) void fused_kernel(
    const float* __restrict__ x, const int* __restrict__ ei,
    const float* __restrict__ ea,
    const float* __restrict__ W1, const float* __restrict__ b1,
    const float* __restrict__ W2, const float* __restrict__ b2,
    float* __restrict__ out,
    float* __restrict__ xa, float* __restrict__ xb,
    int* __restrict__ perm, int* __restrict__ ssrc, int* __restrict__ sdst,
    int* __restrict__ cnt, int* __restrict__ partials)
{
    cg::grid_group grid = cg::this_grid();
    __shared__ int sscan[256];

    const int tid = blockIdx.x * 256 + threadIdx.x;
    const int nthreads = gridDim.x * 256;
    const int w = threadIdx.x >> 6;
    const int l = threadIdx.x & 63;
    const int gw = blockIdx.x * 4 + w;
    const int nwaves = gridDim.x * 4;

    // ---- P0: zero out + cnt ; compute xa/xb ----
    for (int i = tid; i < N_NODES * 16; i += nthreads) {       // 3.2M floats / 4
        float4 z = {0.f, 0.f, 0.f, 0.f};
        ((float4*)out)[i] = z;
    }
    for (int i = tid; i < N_NODES; i += nthreads) cnt[i] = 0;
    pre_phase(gw, nwaves, l, x, W1, xa, xb);
    __threadfence(); grid.sync(); __threadfence();

    // ---- P1: hist over dst ----
    for (int e = tid; e < N_EDGES; e += nthreads)
        atomicAdd(&cnt[ei[N_EDGES + e]], 1);
    __threadfence(); grid.sync(); __threadfence();

    // ---- P2a: per-block scan (tid<=N_NODES; nthreads >= 50176 guaranteed) ----
    const int v = (tid < N_NODES) ? cnt[tid] : 0;
    sscan[threadIdx.x] = v;
    __syncthreads();
    for (int off = 1; off < 256; off <<= 1) {
        const int t = (threadIdx.x >= off) ? sscan[threadIdx.x - off] : 0;
        __syncthreads();
        sscan[threadIdx.x] += t;
        __syncthreads();
    }
    const int incl = sscan[threadIdx.x];
    const int excl = incl - v;
    if (threadIdx.x == 255) partials[blockIdx.x] = incl;
    __threadfence(); grid.sync(); __threadfence();

    // ---- P2b: block 0 exclusive-scans partials[0..G) ----
    if (blockIdx.x == 0) {
        const int G = gridDim.x;
        const int per = (G + 255) / 256;        // <= 8 (G capped at 1280)
        int loc[8];
        int s = 0;
#pragma unroll
        for (int i2 = 0; i2 < 8; ++i2) {
            const int idx = threadIdx.x * per + i2;
            const int c = (i2 < per && idx < G) ? partials[idx] : 0;
            loc[i2] = s; s += c;
        }
        sscan[threadIdx.x] = s;
        __syncthreads();
        for (int off = 1; off < 256; off <<= 1) {
            const int t = (threadIdx.x >= off) ? sscan[threadIdx.x - off] : 0;
            __syncthreads();
            sscan[threadIdx.x] += t;
            __syncthreads();
        }
        const int ex = sscan[threadIdx.x] - s;
#pragma unroll
        for (int i2 = 0; i2 < 8; ++i2) {
            const int idx = threadIdx.x * per + i2;
            if (i2 < per && idx < G) partials[idx] = ex + loc[i2];
        }
    }
    __threadfence(); grid.sync(); __threadfence();

    // ---- P2c: cursor = global exclusive prefix (reuse cnt; atomic for safety) ----
    if (tid < N_NODES) atomicExch(&cnt[tid], excl + partials[blockIdx.x]);
    __threadfence(); grid.sync(); __threadfence();

    // ---- P3: scatter sorted-by-dst ----
    for (int e = tid; e < N_EDGES; e += nthreads) {
        const int d = ei[N_EDGES + e];
        const int s = ei[e];
        const int p = atomicAdd(&cnt[d], 1);
        perm[p] = e; ssrc[p] = s; sdst[p] = d;
    }
    __threadfence(); grid.sync(); __threadfence();

    // ---- P4: edge MLP + merge ----
    edge_phase(gw, nwaves, w, l, xa, xb, perm, ssrc, sdst,
               ea, W1, b1, W2, b2, out);
}

// ---------------------------------------------------------------------------
// Fallback chain (if cooperative launch unavailable): round-5 style
// ---------------------------------------------------------------------------
__global__ __launch_bounds__(256) void pre_kernel(
    const float* __restrict__ x, const float* __restrict__ W1,
    float* __restrict__ xa, float* __restrict__ xb)
{
    pre_phase(blockIdx.x * 4 + (threadIdx.x >> 6), gridDim.x * 4,
              threadIdx.x & 63, x, W1, xa, xb);
}

__global__ __launch_bounds__(256) void hist_kernel(
    const int* __restrict__ ei, int* __restrict__ cnt)
{
    const int e = blockIdx.x * 256 + threadIdx.x;
    if (e < N_EDGES) atomicAdd(&cnt[ei[N_EDGES + e]], 1);
}

__global__ __launch_bounds__(1024) void scan_kernel(int* __restrict__ cnt)
{
    __shared__ int part[1024];
    const int t = threadIdx.x;
    const int base = t * 49;
    int s = 0;
#pragma unroll 7
    for (int i = 0; i < 49; ++i) {
        const int idx = base + i;
        if (idx < N_NODES) s += cnt[idx];
    }
    part[t] = s;
    __syncthreads();
    for (int off = 1; off < 1024; off <<= 1) {
        const int v = (t >= off) ? part[t - off] : 0;
        __syncthreads();
        part[t] += v;
        __syncthreads();
    }
    int run = (t > 0) ? part[t - 1] : 0;
    for (int i = 0; i < 49; ++i) {
        const int idx = base + i;
        if (idx < N_NODES) { const int c = cnt[idx]; cnt[idx] = run; run += c; }
    }
}

__global__ __launch_bounds__(256) void scatter_kernel(
    const int* __restrict__ ei, int* __restrict__ cur,
    int* __restrict__ perm, int* __restrict__ ssrc, int* __restrict__ sdst)
{
    const int e = blockIdx.x * 256 + threadIdx.x;
    if (e < N_EDGES) {
        const int d = ei[N_EDGES + e];
        const int s = ei[e];
        const int p = atomicAdd(&cur[d], 1);
        perm[p] = e; ssrc[p] = s; sdst[p] = d;
    }
}

__global__ __launch_bounds__(256) void edge_sorted_kernel(
    const float* __restrict__ xa, const float* __restrict__ xb,
    const int* __restrict__ perm, const int* __restrict__ ssrc,
    const int* __restrict__ sdst,
    const float* __restrict__ ea,
    const float* __restrict__ W1, const float* __restrict__ b1,
    const float* __restrict__ W2, const float* __restrict__ b2,
    float* __restrict__ out)
{
    edge_phase(blockIdx.x * 4 + (threadIdx.x >> 6), gridDim.x * 4,
               threadIdx.x >> 6, threadIdx.x & 63,
               xa, xb, perm, ssrc, sdst, ea, W1, b1, W2, b2, out);
}

// last-resort (tiny ws): one wave per edge, full 144-dot (round-2, passed)
__global__ __launch_bounds__(256) void fallback_kernel(
    const float* __restrict__ x, const int* __restrict__ ei,
    const float* __restrict__ edge_attr,
    const float* __restrict__ W1, const float* __restrict__ b1,
    const float* __restrict__ W2, const float* __restrict__ b2,
    float* __restrict__ out)
{
    const int w = threadIdx.x >> 6;
    const int j = threadIdx.x & 63;
    const long e = (long)blockIdx.x * 4 + w;
    if (e >= N_EDGES) return;
    const int s  = ei[e];
    const int dd = ei[(long)N_EDGES + e];

    float acc = b1[j];
    for (int k = 0; k < 64; ++k) acc += x[(long)s  * 64 + k] * W1[k * 64 + j];
    for (int k = 0; k < 64; ++k) acc += x[(long)dd * 64 + k] * W1[(64 + k) * 64 + j];
    for (int k = 0; k < 16; ++k) acc += edge_attr[e * 16 + k] * W1[(128 + k) * 64 + j];
    const float h = fmaxf(acc, 0.f);

    float msg = b2[j];
    for (int k = 0; k < 64; ++k) msg += __shfl(h, k) * W2[k * 64 + j];
    unsafeAtomicAdd(&out[(long)dd * 64 + j], msg);
}

extern "C" void kernel_launch(void* const* d_in, const int* in_sizes, int n_in,
                              void* d_out, int out_size, void* d_ws, size_t ws_size,
                              hipStream_t stream) {
    const float* x   = (const float*)d_in[0];
    const int*   ei  = (const int*)d_in[1];
    const float* ea  = (const float*)d_in[2];
    const float* W1  = (const float*)d_in[3];
    const float* b1  = (const float*)d_in[4];
    const float* W2  = (const float*)d_in[5];
    const float* b2  = (const float*)d_in[6];
    float* out = (float*)d_out;

    // workspace carve
    float* xa   = (float*)d_ws;
    float* xb   = xa + (size_t)N_NODES * 64;
    int* perm   = (int*)(xb + (size_t)N_NODES * 64);
    int* ssrc   = perm + N_EDGES;
    int* sdst   = ssrc + N_EDGES;
    int* cnt    = sdst + N_EDGES;
    int* parts  = cnt + N_NODES;
    const size_t need_full = (size_t)((char*)(parts + 2048) - (char*)d_ws);
    const size_t need_base = (size_t)2 * N_NODES * 64 * sizeof(float);

    if (ws_size >= need_full) {
        int nb = 0;
        hipError_t oe = hipOccupancyMaxActiveBlocksPerMultiprocessor(
            &nb, (const void*)fused_kernel, 256, 0);
        int G = (oe == hipSuccess && nb > 0) ? nb * 256 : 512;
        if (G > 1280) G = 1280;
        if (G < 256)  G = 256;       // scan needs >= 50176 threads

        void* args[] = { (void*)&x, (void*)&ei, (void*)&ea, (void*)&W1,
                         (void*)&b1, (void*)&W2, (void*)&b2, (void*)&out,
                         (void*)&xa, (void*)&xb, (void*)&perm, (void*)&ssrc,
                         (void*)&sdst, (void*)&cnt, (void*)&parts };
        hipError_t err = hipLaunchCooperativeKernel(
            (const void*)fused_kernel, dim3(G), dim3(256), args, 0, stream);
        if (err == hipSuccess) return;

        // cooperative unavailable: serialized chain (round-5 structure)
        hipMemsetAsync(out, 0, (size_t)N_NODES * 64 * sizeof(float), stream);
        hipMemsetAsync(cnt, 0, (size_t)N_NODES * sizeof(int), stream);
        pre_kernel<<<1024, 256, 0, stream>>>(x, W1, xa, xb);
        hist_kernel<<<(N_EDGES + 255) / 256, 256, 0, stream>>>(ei, cnt);
        scan_kernel<<<1, 1024, 0, stream>>>(cnt);
        scatter_kernel<<<(N_EDGES + 255) / 256, 256, 0, stream>>>(ei, cnt, perm, ssrc, sdst);
        edge_sorted_kernel<<<1024, 256, 0, stream>>>(xa, xb, perm, ssrc, sdst,
                                                     ea, W1, b1, W2, b2, out);
    } else {
        hipMemsetAsync(out, 0, (size_t)N_NODES * 64 * sizeof(float), stream);
        fallback_kernel<<<N_EDGES / 4, 256, 0, stream>>>(x, ei, ea,
                                                         W1, b1, W2, b2, out);
    }
}

// Round 8
// 818.581 us; speedup vs baseline: 1.6404x; 1.6404x over previous
//
#include <hip/hip_runtime.h>
#include <hip/hip_cooperative_groups.h>

namespace cg = cooperative_groups;

#define N_NODES 50000
#define N_EDGES 800000
#define NTILES  (N_EDGES / 16)
// IN_F = 64, OUT_F = 64, EDGE_F = 16. edge_index int32[2*E]: src=ei[e], dst=ei[E+e].
//
// One cooperative kernel, phases separated by grid.sync():
//   P0: zero out+cnt, xa=x@W1[0:64], xb=x@W1[64:128]
//   P1: hist(dst) -> cnt
//   P2: grid-wide exclusive scan of cnt
//   P3: scatter: perm/ssrc/sdst sorted by dst
//   P4: 16-edge MFMA tiles + run-merge epilogue (~6M atomics @ ~274G/s wall)
//
// Round-6 lesson: __launch_bounds__(256,4) made the allocator pick 64 VGPRs and
// spill weight fragments -> 530 MB scratch traffic. Fix: plain bounds(256).
// Round-7 lesson: __noinline__ + __shared__ in a device fn called from two
// kernels kills the build (module-LDS lowering). Keep phases __forceinline__.
// RULE: __shfl only in wave-uniform control flow (round-4 lesson).

typedef __attribute__((ext_vector_type(8))) short bf16x8;  // 8 bf16 = 4 VGPRs
typedef __attribute__((ext_vector_type(4))) float f32x4;

__device__ inline short f2bf(float f) {       // fp32 -> bf16 bits, RNE
    union { float f; unsigned u; } v; v.f = f;
    unsigned r = v.u + 0x7FFFu + ((v.u >> 16) & 1u);
    return (short)(r >> 16);
}

// ---------------------------------------------------------------------------
// pre phase: xa = x @ W1[0:64,:], xb = x @ W1[64:128,:]  (fp32)
// ---------------------------------------------------------------------------
__device__ __forceinline__ void pre_phase(
    int gw, int nwaves, int j,
    const float* __restrict__ x, const float* __restrict__ W1,
    float* __restrict__ xa, float* __restrict__ xb)
{
    const int p = gw & 1;
    const int pair = gw >> 1;
    const int npair = nwaves >> 1;

    float wc[64];
#pragma unroll
    for (int k = 0; k < 64; ++k) wc[k] = W1[(p * 64 + k) * 64 + j];

    float* __restrict__ outp = p ? xb : xa;

    for (int i = pair; i < N_NODES; i += npair) {
        const float4* xr = (const float4*)&x[(long)i * 64];
        float a0 = 0.f, a1 = 0.f, a2 = 0.f, a3 = 0.f;
#pragma unroll
        for (int k4 = 0; k4 < 16; ++k4) {
            float4 xv = xr[k4];
            a0 += xv.x * wc[k4 * 4 + 0];
            a1 += xv.y * wc[k4 * 4 + 1];
            a2 += xv.z * wc[k4 * 4 + 2];
            a3 += xv.w * wc[k4 * 4 + 3];
        }
        outp[(long)i * 64 + j] = (a0 + a1) + (a2 + a3);
    }
}

// ---------------------------------------------------------------------------
// edge phase: tiles of 16 dst-sorted edges; next-tile index prefetch.
//   C1(16x64) = EA(16x16 pad32) @ W1c ; h = relu(C1 + xa[src]+xb[dst]+b1)
//   C2(16x64) = h @ W2 ; run-merge equal-dst rows -> one atomic per run
// MFMA 16x16x32: A: m=lane&15,k=(lane>>4)*8+i ; B: n=lane&15 same k
//                C: n=lane&15, m=(lane>>4)*4+r
// ---------------------------------------------------------------------------
union __align__(16) TileMem {
    unsigned short h[16][72];   // bf16 hidden (used first)
    float          m[16][68];   // fp32 msg (used after h is consumed)
};

__device__ __forceinline__ void edge_phase(
    int gw, int nwaves, int w, int l,
    const float* __restrict__ xa, const float* __restrict__ xb,
    const int* __restrict__ perm, const int* __restrict__ ssrc,
    const int* __restrict__ sdst,
    const float* __restrict__ edge_attr,
    const float* __restrict__ W1, const float* __restrict__ b1,
    const float* __restrict__ W2, const float* __restrict__ b2,
    float* __restrict__ out)
{
    __shared__ TileMem tls[4];
    __shared__ int dstbuf[4][16];

    const int n = l & 15;          // C col / A row / B col
    const int q = l >> 4;          // quad

    bf16x8 w1f[4];                 // W1 rows 128..143 (K-padded)
    bf16x8 w2f[4][2];
    float b1v[4], b2v[4];
#pragma unroll
    for (int t = 0; t < 4; ++t) {
        const int col = t * 16 + n;
#pragma unroll
        for (int i = 0; i < 8; ++i) {
            const int k = q * 8 + i;
            w1f[t][i] = (q < 2) ? f2bf(W1[(128 + k) * 64 + col]) : (short)0;
            w2f[t][0][i] = f2bf(W2[k * 64 + col]);
            w2f[t][1][i] = f2bf(W2[(32 + k) * 64 + col]);
        }
        b1v[t] = b1[col];
        b2v[t] = b2[col];
    }

    // prefetched indices for the first tile (all lanes: row l&15 of the tile)
    int pev = 0, sv = 0, dv = 0;
    if (gw < NTILES) {
        const long eb0 = (long)gw * 16;
        pev = perm[eb0 + n]; sv = ssrc[eb0 + n]; dv = sdst[eb0 + n];
    }

    for (int tile = gw; tile < NTILES; tile += nwaves) {
        const int cpev = pev, csv = sv, cdv = dv;

        // issue next tile's index loads now (latency hidden by this tile)
        const int nt = tile + nwaves;
        if (nt < NTILES) {
            const long neb = (long)nt * 16;
            pev = perm[neb + n]; sv = ssrc[neb + n]; dv = sdst[neb + n];
        }

        // edge_attr loads issue immediately (cpev already resident)
        float4 e0, e1;
        if (q < 2) {
            const float* ep = &edge_attr[(long)cpev * 16 + q * 8];
            e0 = *(const float4*)ep;
            e1 = *(const float4*)(ep + 4);
        }

        if (l < 16) dstbuf[w][n] = cdv;

        // uniform-exec shfls
        int srcr[4], dstr[4];
#pragma unroll
        for (int r = 0; r < 4; ++r) {
            srcr[r] = __shfl(csv, q * 4 + r);
            dstr[r] = __shfl(cdv, q * 4 + r);
        }

        // gather xa[src]+xb[dst] in C layout (xb near-uniform after sort)
        float g[4][4];
#pragma unroll
        for (int t = 0; t < 4; ++t)
#pragma unroll
            for (int r = 0; r < 4; ++r)
                g[t][r] = xa[(long)srcr[r] * 64 + t * 16 + n]
                        + xb[(long)dstr[r] * 64 + t * 16 + n];

        // edge_attr A-fragment (K pad: quads 2,3 zero)
        bf16x8 eaf;
        if (q < 2) {
            eaf[0] = f2bf(e0.x); eaf[1] = f2bf(e0.y);
            eaf[2] = f2bf(e0.z); eaf[3] = f2bf(e0.w);
            eaf[4] = f2bf(e1.x); eaf[5] = f2bf(e1.y);
            eaf[6] = f2bf(e1.z); eaf[7] = f2bf(e1.w);
        } else {
#pragma unroll
            for (int i = 0; i < 8; ++i) eaf[i] = (short)0;
        }

        // GEMM1c
        f32x4 c1[4];
#pragma unroll
        for (int t = 0; t < 4; ++t) {
            f32x4 z = {0.f, 0.f, 0.f, 0.f};
            c1[t] = __builtin_amdgcn_mfma_f32_16x16x32_bf16(eaf, w1f[t], z, 0, 0, 0);
        }

        // h = relu(c1+g+b1) -> bf16 -> LDS (C layout)
#pragma unroll
        for (int t = 0; t < 4; ++t)
#pragma unroll
            for (int r = 0; r < 4; ++r) {
                const float h = fmaxf(c1[t][r] + g[t][r] + b1v[t], 0.f);
                tls[w].h[q * 4 + r][t * 16 + n] = (unsigned short)f2bf(h);
            }

        // h as A-fragments (wave-internal, DS in-order)
        bf16x8 hf0 = *(const bf16x8*)&tls[w].h[n][q * 8];
        bf16x8 hf1 = *(const bf16x8*)&tls[w].h[n][32 + q * 8];

        // GEMM2
        f32x4 c2[4];
#pragma unroll
        for (int t = 0; t < 4; ++t) {
            f32x4 z = {0.f, 0.f, 0.f, 0.f};
            c2[t] = __builtin_amdgcn_mfma_f32_16x16x32_bf16(hf0, w2f[t][0], z, 0, 0, 0);
            c2[t] = __builtin_amdgcn_mfma_f32_16x16x32_bf16(hf1, w2f[t][1], c2[t], 0, 0, 0);
        }

        // msg -> LDS row-major (overlays h: h fully consumed above)
#pragma unroll
        for (int t = 0; t < 4; ++t)
#pragma unroll
            for (int r = 0; r < 4; ++r)
                tls[w].m[q * 4 + r][t * 16 + n] = c2[t][r] + b2v[t];

        // run-merge: lane l owns column l; rows sorted by dst (uniform branches)
        {
            int cur = dstbuf[w][0];
            float acc = tls[w].m[0][l];
#pragma unroll
            for (int r16 = 1; r16 < 16; ++r16) {
                const int d2 = dstbuf[w][r16];
                const float v = tls[w].m[r16][l];
                if (d2 != cur) {
                    unsafeAtomicAdd(&out[(long)cur * 64 + l], acc);
                    cur = d2; acc = v;
                } else {
                    acc += v;
                }
            }
            unsafeAtomicAdd(&out[(long)cur * 64 + l], acc);
        }
    }
}

// ---------------------------------------------------------------------------
// THE fused cooperative kernel (no min-waves bound: let the allocator breathe)
// ---------------------------------------------------------------------------
__global__ __launch_bounds__(256) void fused_kernel(
    const float* __restrict__ x, const int* __restrict__ ei,
    const float* __restrict__ ea,
    const float* __restrict__ W1, const float* __restrict__ b1,
    const float* __restrict__ W2, const float* __restrict__ b2,
    float* __restrict__ out,
    float* __restrict__ xa, float* __restrict__ xb,
    int* __restrict__ perm, int* __restrict__ ssrc, int* __restrict__ sdst,
    int* __restrict__ cnt, int* __restrict__ partials)
{
    cg::grid_group grid = cg::this_grid();
    __shared__ int sscan[256];

    const int tid = blockIdx.x * 256 + threadIdx.x;
    const int nthreads = gridDim.x * 256;
    const int w = threadIdx.x >> 6;
    const int l = threadIdx.x & 63;
    const int gw = blockIdx.x * 4 + w;
    const int nwaves = gridDim.x * 4;

    // ---- P0: zero out + cnt ; compute xa/xb ----
    for (int i = tid; i < N_NODES * 16; i += nthreads) {       // 3.2M floats / 4
        float4 z = {0.f, 0.f, 0.f, 0.f};
        ((float4*)out)[i] = z;
    }
    for (int i = tid; i < N_NODES; i += nthreads) cnt[i] = 0;
    pre_phase(gw, nwaves, l, x, W1, xa, xb);
    __threadfence(); grid.sync(); __threadfence();

    // ---- P1: hist over dst ----
    for (int e = tid; e < N_EDGES; e += nthreads)
        atomicAdd(&cnt[ei[N_EDGES + e]], 1);
    __threadfence(); grid.sync(); __threadfence();

    // ---- P2a: per-block scan (needs nthreads >= N_NODES) ----
    const int v = (tid < N_NODES) ? cnt[tid] : 0;
    sscan[threadIdx.x] = v;
    __syncthreads();
    for (int off = 1; off < 256; off <<= 1) {
        const int t = (threadIdx.x >= off) ? sscan[threadIdx.x - off] : 0;
        __syncthreads();
        sscan[threadIdx.x] += t;
        __syncthreads();
    }
    const int incl = sscan[threadIdx.x];
    const int excl = incl - v;
    if (threadIdx.x == 255) partials[blockIdx.x] = incl;
    __threadfence(); grid.sync(); __threadfence();

    // ---- P2b: block 0 exclusive-scans partials[0..G) ----
    if (blockIdx.x == 0) {
        const int G = gridDim.x;
        const int per = (G + 255) / 256;        // <= 8 (G capped at 2048)
        int loc[8];
        int s = 0;
#pragma unroll
        for (int i2 = 0; i2 < 8; ++i2) {
            const int idx = threadIdx.x * per + i2;
            const int c = (i2 < per && idx < G) ? partials[idx] : 0;
            loc[i2] = s; s += c;
        }
        sscan[threadIdx.x] = s;
        __syncthreads();
        for (int off = 1; off < 256; off <<= 1) {
            const int t = (threadIdx.x >= off) ? sscan[threadIdx.x - off] : 0;
            __syncthreads();
            sscan[threadIdx.x] += t;
            __syncthreads();
        }
        const int ex = sscan[threadIdx.x] - s;
#pragma unroll
        for (int i2 = 0; i2 < 8; ++i2) {
            const int idx = threadIdx.x * per + i2;
            if (i2 < per && idx < G) partials[idx] = ex + loc[i2];
        }
    }
    __threadfence(); grid.sync(); __threadfence();

    // ---- P2c: cursor = global exclusive prefix (reuse cnt) ----
    if (tid < N_NODES) atomicExch(&cnt[tid], excl + partials[blockIdx.x]);
    __threadfence(); grid.sync(); __threadfence();

    // ---- P3: scatter sorted-by-dst ----
    for (int e = tid; e < N_EDGES; e += nthreads) {
        const int d = ei[N_EDGES + e];
        const int s = ei[e];
        const int p = atomicAdd(&cnt[d], 1);
        perm[p] = e; ssrc[p] = s; sdst[p] = d;
    }
    __threadfence(); grid.sync(); __threadfence();

    // ---- P4: edge MLP + merge ----
    edge_phase(gw, nwaves, w, l, xa, xb, perm, ssrc, sdst,
               ea, W1, b1, W2, b2, out);
}

// ---------------------------------------------------------------------------
// Fallback chain (if cooperative launch unavailable): round-5 style
// ---------------------------------------------------------------------------
__global__ __launch_bounds__(256) void pre_kernel(
    const float* __restrict__ x, const float* __restrict__ W1,
    float* __restrict__ xa, float* __restrict__ xb)
{
    pre_phase(blockIdx.x * 4 + (threadIdx.x >> 6), gridDim.x * 4,
              threadIdx.x & 63, x, W1, xa, xb);
}

__global__ __launch_bounds__(256) void hist_kernel(
    const int* __restrict__ ei, int* __restrict__ cnt)
{
    const int e = blockIdx.x * 256 + threadIdx.x;
    if (e < N_EDGES) atomicAdd(&cnt[ei[N_EDGES + e]], 1);
}

__global__ __launch_bounds__(1024) void scan_kernel(int* __restrict__ cnt)
{
    __shared__ int part[1024];
    const int t = threadIdx.x;
    const int base = t * 49;
    int s = 0;
#pragma unroll 7
    for (int i = 0; i < 49; ++i) {
        const int idx = base + i;
        if (idx < N_NODES) s += cnt[idx];
    }
    part[t] = s;
    __syncthreads();
    for (int off = 1; off < 1024; off <<= 1) {
        const int v = (t >= off) ? part[t - off] : 0;
        __syncthreads();
        part[t] += v;
        __syncthreads();
    }
    int run = (t > 0) ? part[t - 1] : 0;
    for (int i = 0; i < 49; ++i) {
        const int idx = base + i;
        if (idx < N_NODES) { const int c = cnt[idx]; cnt[idx] = run; run += c; }
    }
}

__global__ __launch_bounds__(256) void scatter_kernel(
    const int* __restrict__ ei, int* __restrict__ cur,
    int* __restrict__ perm, int* __restrict__ ssrc, int* __restrict__ sdst)
{
    const int e = blockIdx.x * 256 + threadIdx.x;
    if (e < N_EDGES) {
        const int d = ei[N_EDGES + e];
        const int s = ei[e];
        const int p = atomicAdd(&cur[d], 1);
        perm[p] = e; ssrc[p] = s; sdst[p] = d;
    }
}

__global__ __launch_bounds__(256) void edge_sorted_kernel(
    const float* __restrict__ xa, const float* __restrict__ xb,
    const int* __restrict__ perm, const int* __restrict__ ssrc,
    const int* __restrict__ sdst,
    const float* __restrict__ ea,
    const float* __restrict__ W1, const float* __restrict__ b1,
    const float* __restrict__ W2, const float* __restrict__ b2,
    float* __restrict__ out)
{
    edge_phase(blockIdx.x * 4 + (threadIdx.x >> 6), gridDim.x * 4,
               threadIdx.x >> 6, threadIdx.x & 63,
               xa, xb, perm, ssrc, sdst, ea, W1, b1, W2, b2, out);
}

// last-resort (tiny ws): one wave per edge, full 144-dot (round-2, passed)
__global__ __launch_bounds__(256) void fallback_kernel(
    const float* __restrict__ x, const int* __restrict__ ei,
    const float* __restrict__ edge_attr,
    const float* __restrict__ W1, const float* __restrict__ b1,
    const float* __restrict__ W2, const float* __restrict__ b2,
    float* __restrict__ out)
{
    const int w = threadIdx.x >> 6;
    const int j = threadIdx.x & 63;
    const long e = (long)blockIdx.x * 4 + w;
    if (e >= N_EDGES) return;
    const int s  = ei[e];
    const int dd = ei[(long)N_EDGES + e];

    float acc = b1[j];
    for (int k = 0; k < 64; ++k) acc += x[(long)s  * 64 + k] * W1[k * 64 + j];
    for (int k = 0; k < 64; ++k) acc += x[(long)dd * 64 + k] * W1[(64 + k) * 64 + j];
    for (int k = 0; k < 16; ++k) acc += edge_attr[e * 16 + k] * W1[(128 + k) * 64 + j];
    const float h = fmaxf(acc, 0.f);

    float msg = b2[j];
    for (int k = 0; k < 64; ++k) msg += __shfl(h, k) * W2[k * 64 + j];
    unsafeAtomicAdd(&out[(long)dd * 64 + j], msg);
}

extern "C" void kernel_launch(void* const* d_in, const int* in_sizes, int n_in,
                              void* d_out, int out_size, void* d_ws, size_t ws_size,
                              hipStream_t stream) {
    const float* x   = (const float*)d_in[0];
    const int*   ei  = (const int*)d_in[1];
    const float* ea  = (const float*)d_in[2];
    const float* W1  = (const float*)d_in[3];
    const float* b1  = (const float*)d_in[4];
    const float* W2  = (const float*)d_in[5];
    const float* b2  = (const float*)d_in[6];
    float* out = (float*)d_out;

    // workspace carve
    float* xa   = (float*)d_ws;
    float* xb   = xa + (size_t)N_NODES * 64;
    int* perm   = (int*)(xb + (size_t)N_NODES * 64);
    int* ssrc   = perm + N_EDGES;
    int* sdst   = ssrc + N_EDGES;
    int* cnt    = sdst + N_EDGES;
    int* parts  = cnt + N_NODES;
    const size_t need_full = (size_t)((char*)(parts + 2048) - (char*)d_ws);

    if (ws_size >= need_full) {
        int nb = 0;
        hipError_t oe = hipOccupancyMaxActiveBlocksPerMultiprocessor(
            &nb, (const void*)fused_kernel, 256, 0);
        int G = (oe == hipSuccess && nb > 0) ? nb * 256 : 512;
        if (G > 2048) G = 2048;
        if (G < 256)  G = 256;       // P2a scan needs >= 50176 threads

        void* args[] = { (void*)&x, (void*)&ei, (void*)&ea, (void*)&W1,
                         (void*)&b1, (void*)&W2, (void*)&b2, (void*)&out,
                         (void*)&xa, (void*)&xb, (void*)&perm, (void*)&ssrc,
                         (void*)&sdst, (void*)&cnt, (void*)&parts };
        hipError_t err = hipLaunchCooperativeKernel(
            (const void*)fused_kernel, dim3(G), dim3(256), args, 0, stream);
        if (err == hipSuccess) return;

        // cooperative unavailable: serialized chain (round-5 structure)
        hipMemsetAsync(out, 0, (size_t)N_NODES * 64 * sizeof(float), stream);
        hipMemsetAsync(cnt, 0, (size_t)N_NODES * sizeof(int), stream);
        pre_kernel<<<1024, 256, 0, stream>>>(x, W1, xa, xb);
        hist_kernel<<<(N_EDGES + 255) / 256, 256, 0, stream>>>(ei, cnt);
        scan_kernel<<<1, 1024, 0, stream>>>(cnt);
        scatter_kernel<<<(N_EDGES + 255) / 256, 256, 0, stream>>>(ei, cnt, perm, ssrc, sdst);
        edge_sorted_kernel<<<1024, 256, 0, stream>>>(xa, xb, perm, ssrc, sdst,
                                                     ea, W1, b1, W2, b2, out);
    } else {
        hipMemsetAsync(out, 0, (size_t)N_NODES * 64 * sizeof(float), stream);
        fallback_kernel<<<N_EDGES / 4, 256, 0, stream>>>(x, ei, ea,
                                                         W1, b1, W2, b2, out);
    }
}